// Round 1
// baseline (2360.194 us; speedup 1.0000x reference)
//
#include <hip/hip_runtime.h>
#include <cmath>

#define DH 256
#define G3 768
#define DIN 300
#define NLEAF 16384

__device__ __forceinline__ float sigm(float x){ return 1.0f/(1.0f+expf(-x)); }
__device__ __forceinline__ float dot4(float4 a, float4 b, float acc){
    acc = fmaf(a.x,b.x,acc); acc = fmaf(a.y,b.y,acc);
    acc = fmaf(a.z,b.z,acc); acc = fmaf(a.w,b.w,acc);
    return acc;
}

// Transpose weights into [col(0..767)][k] layout so the GEMV k-loop does float4 loads.
__global__ void prep_kernel(const float* __restrict__ Wx, const float* __restrict__ Wc,
                            const float* __restrict__ Ws, float* __restrict__ Wxt,
                            float* __restrict__ Wct, float* __restrict__ Wst){
    int idx = blockIdx.x*256 + threadIdx.x;
    if (idx < G3*DIN){ int c = idx / DIN, k = idx - c*DIN; Wxt[idx] = Wx[k*G3 + c]; return; }
    idx -= G3*DIN;
    if (idx < G3*DH){ int c = idx >> 8, k = idx & 255; Wct[idx] = Wc[k*G3 + c]; return; }
    idx -= G3*DH;
    if (idx < G3*DH){ int c = idx >> 8, k = idx & 255; Wst[idx] = Ws[k*G3 + c]; }
}

// Leaf: 32 rows per WG, 512 threads. Thread owns column (tid&255) x 3 gates for 16 rows.
__global__ __launch_bounds__(512,4) void leaf_kernel(const int* __restrict__ wid,
        const float* __restrict__ emb, const float* __restrict__ Wxt,
        const float* __restrict__ bx, float* __restrict__ h_out, float* __restrict__ c_out){
    __shared__ float xs[32][DIN];   // 38.4 KB
    __shared__ int swid[32];
    const int tid = threadIdx.x;
    const int base = blockIdx.x * 32;
    if (tid < 32) swid[tid] = wid[base + tid];
    __syncthreads();
    for (int idx = tid; idx < 32*DIN; idx += 512){
        int r = idx / DIN, k = idx - r*DIN;
        xs[r][k] = emb[swid[r]*DIN + k];
    }
    __syncthreads();
    const int col = tid & 255, half = tid >> 8;
    float a0[16], a1[16], a2[16];
    #pragma unroll
    for (int i=0;i<16;++i){ a0[i]=0.f; a1[i]=0.f; a2[i]=0.f; }
    const float* w0p = Wxt + col*DIN;
    const float* w1p = Wxt + (DH+col)*DIN;
    const float* w2p = Wxt + (2*DH+col)*DIN;
    for (int k4 = 0; k4 < DIN/4; ++k4){
        float4 w0 = *(const float4*)(w0p + 4*k4);
        float4 w1 = *(const float4*)(w1p + 4*k4);
        float4 w2 = *(const float4*)(w2p + 4*k4);
        #pragma unroll
        for (int i=0;i<16;++i){
            float4 xv = *(const float4*)&xs[half*16+i][4*k4];
            a0[i]=dot4(xv,w0,a0[i]); a1[i]=dot4(xv,w1,a1[i]); a2[i]=dot4(xv,w2,a2[i]);
        }
    }
    const float b0 = bx[col], b1 = bx[DH+col], b2 = bx[2*DH+col];
    #pragma unroll
    for (int i=0;i<16;++i){
        int r = base + half*16 + i;
        // gi, go, cpre order per reference leaf
        float c = sigm(a0[i]+b0) * tanhf(a2[i]+b2);
        float h = sigm(a1[i]+b1) * tanhf(c);
        h_out[r*DH+col] = h; c_out[r*DH+col] = c;
    }
}

// One level: parents p get children (2p, 2p+1). Fused left-combine + parent combine.
// RH = parent rows per half (PP = 2*RH parents per 512-thread WG).
template<int RH>
__global__ __launch_bounds__(512,4) void level_kernel(const float* __restrict__ h_in,
        const float* __restrict__ c_in, float* __restrict__ h_out, float* __restrict__ c_out,
        const float* __restrict__ Wct, const float* __restrict__ Wst,
        const float* __restrict__ bs, const float* __restrict__ bc, const int P){
    constexpr int PP = 2*RH;
    __shared__ float hstage[PP][DH];
    __shared__ float hlsh[PP][DH];
    const int tid = threadIdx.x;
    const int pbase = blockIdx.x * PP;
    // stage left children h (even rows)
    for (int idx = tid; idx < PP*DH; idx += 512){
        int r = idx >> 8, k = idx & 255;
        hstage[r][k] = h_in[((pbase+r)*2)*DH + k];
    }
    __syncthreads();
    const int col = tid & 255, half = tid >> 8;
    const float bb0 = bs[col]+bc[col];
    const float bb1 = bs[DH+col]+bc[DH+col];
    const float bb2 = bs[2*DH+col]+bc[2*DH+col];
    const float* wc0 = Wct + col*DH;
    const float* wc1 = Wct + (DH+col)*DH;
    const float* wc2 = Wct + (2*DH+col)*DH;
    // Phase 1: left combine needs only gc, go gates
    float a1[RH], a2[RH];
    #pragma unroll
    for (int i=0;i<RH;++i){ a1[i]=0.f; a2[i]=0.f; }
    for (int k4=0;k4<DH/4;++k4){
        float4 w1 = *(const float4*)(wc1 + 4*k4);
        float4 w2 = *(const float4*)(wc2 + 4*k4);
        #pragma unroll
        for (int i=0;i<RH;++i){
            float4 hv = *(const float4*)&hstage[half*RH+i][4*k4];
            a1[i]=dot4(hv,w1,a1[i]); a2[i]=dot4(hv,w2,a2[i]);
        }
    }
    float clr[RH];
    #pragma unroll
    for (int i=0;i<RH;++i){
        int r = half*RH+i; int p = pbase + r;
        float cl = sigm(a1[i]+bb1) * c_in[(p*2)*DH + col];
        float hl = sigm(a2[i]+bb2) * tanhf(cl);
        clr[i] = cl;
        hlsh[r][col] = hl;
    }
    __syncthreads();
    // restage right children (odd rows)
    for (int idx = tid; idx < PP*DH; idx += 512){
        int r = idx >> 8, k = idx & 255;
        hstage[r][k] = h_in[((pbase+r)*2+1)*DH + k];
    }
    __syncthreads();
    // Phase 2: parent g = h_r@Wc + hl@Ws (+biases), two accumulation passes
    float g0[RH], g1[RH], g2[RH];
    #pragma unroll
    for (int i=0;i<RH;++i){ g0[i]=0.f; g1[i]=0.f; g2[i]=0.f; }
    for (int k4=0;k4<DH/4;++k4){
        float4 w0 = *(const float4*)(wc0 + 4*k4);
        float4 w1 = *(const float4*)(wc1 + 4*k4);
        float4 w2 = *(const float4*)(wc2 + 4*k4);
        #pragma unroll
        for (int i=0;i<RH;++i){
            float4 hv = *(const float4*)&hstage[half*RH+i][4*k4];
            g0[i]=dot4(hv,w0,g0[i]); g1[i]=dot4(hv,w1,g1[i]); g2[i]=dot4(hv,w2,g2[i]);
        }
    }
    const float* ws0 = Wst + col*DH;
    const float* ws1 = Wst + (DH+col)*DH;
    const float* ws2 = Wst + (2*DH+col)*DH;
    for (int k4=0;k4<DH/4;++k4){
        float4 w0 = *(const float4*)(ws0 + 4*k4);
        float4 w1 = *(const float4*)(ws1 + 4*k4);
        float4 w2 = *(const float4*)(ws2 + 4*k4);
        #pragma unroll
        for (int i=0;i<RH;++i){
            float4 hv = *(const float4*)&hlsh[half*RH+i][4*k4];
            g0[i]=dot4(hv,w0,g0[i]); g1[i]=dot4(hv,w1,g1[i]); g2[i]=dot4(hv,w2,g2[i]);
        }
    }
    #pragma unroll
    for (int i=0;i<RH;++i){
        int p = pbase + half*RH + i;
        if (p < P){
            float cn = sigm(g1[i]+bb1) * c_in[(p*2+1)*DH + col] + sigm(g0[i]+bb0) * clr[i];
            float hn = sigm(g2[i]+bb2) * tanhf(cn);
            h_out[p*DH+col] = hn;
            c_out[p*DH+col] = cn;
        }
    }
}

__global__ void root_kernel(const float* __restrict__ h_in, const float* __restrict__ c_in,
        const float* __restrict__ Wct, const float* __restrict__ bs,
        const float* __restrict__ bc, float* __restrict__ out){
    __shared__ float hs[DH];
    const int t = threadIdx.x;
    hs[t] = h_in[t];
    __syncthreads();
    float a1=0.f, a2=0.f;
    const float* w1 = Wct + (DH+t)*DH;
    const float* w2 = Wct + (2*DH+t)*DH;
    for (int k4=0;k4<DH/4;++k4){
        float4 hv = *(const float4*)&hs[4*k4];
        a1 = dot4(hv, *(const float4*)(w1+4*k4), a1);
        a2 = dot4(hv, *(const float4*)(w2+4*k4), a2);
    }
    float cn = sigm(a1 + bs[DH+t]+bc[DH+t]) * c_in[t];
    out[t] = sigm(a2 + bs[2*DH+t]+bc[2*DH+t]) * tanhf(cn);
}

extern "C" void kernel_launch(void* const* d_in, const int* in_sizes, int n_in,
                              void* d_out, int out_size, void* d_ws, size_t ws_size,
                              hipStream_t stream){
    const int*   wid = (const int*)d_in[0];
    const float* emb = (const float*)d_in[1];
    const float* Wx  = (const float*)d_in[2];
    const float* bx  = (const float*)d_in[3];
    const float* Ws  = (const float*)d_in[4];
    const float* bs  = (const float*)d_in[5];
    const float* Wc  = (const float*)d_in[6];
    const float* bc  = (const float*)d_in[7];
    float* out = (float*)d_out;

    float* p = (float*)d_ws;
    float* hA = p;            p += NLEAF*DH;
    float* cA = p;            p += NLEAF*DH;
    float* hB = p;            p += (NLEAF/2)*DH;
    float* cB = p;            p += (NLEAF/2)*DH;
    float* Wxt = p;           p += G3*DIN;
    float* Wct = p;           p += G3*DH;
    float* Wst = p;           p += G3*DH;

    const int prep_elems = G3*DIN + 2*G3*DH;
    prep_kernel<<<(prep_elems+255)/256, 256, 0, stream>>>(Wx, Wc, Ws, Wxt, Wct, Wst);
    leaf_kernel<<<NLEAF/32, 512, 0, stream>>>(wid, emb, Wxt, bx, hA, cA);

    float* hin = hA; float* cin = cA; float* hout = hB; float* cout = cB;
    int P = NLEAF/2;
    while (P >= 1){
        const int PPv = (P >= 8192) ? 32 : (P >= 4096) ? 16 : (P >= 2048) ? 8 : (P >= 1024) ? 4 : 2;
        const int grid = (P + PPv - 1)/PPv;
        switch (PPv){
          case 32: level_kernel<16><<<grid,512,0,stream>>>(hin,cin,hout,cout,Wct,Wst,bs,bc,P); break;
          case 16: level_kernel< 8><<<grid,512,0,stream>>>(hin,cin,hout,cout,Wct,Wst,bs,bc,P); break;
          case 8:  level_kernel< 4><<<grid,512,0,stream>>>(hin,cin,hout,cout,Wct,Wst,bs,bc,P); break;
          case 4:  level_kernel< 2><<<grid,512,0,stream>>>(hin,cin,hout,cout,Wct,Wst,bs,bc,P); break;
          default: level_kernel< 1><<<grid,512,0,stream>>>(hin,cin,hout,cout,Wct,Wst,bs,bc,P); break;
        }
        float* t;
        t = hin; hin = hout; hout = t;
        t = cin; cin = cout; cout = t;
        P >>= 1;
    }
    root_kernel<<<1,256,0,stream>>>(hin, cin, Wct, bs, bc, out);
}

// Round 2
// 920.753 us; speedup vs baseline: 2.5633x; 2.5633x over previous
//
#include <hip/hip_runtime.h>
#include <cmath>

typedef _Float16 f16;
typedef _Float16 f16x8 __attribute__((ext_vector_type(8)));
typedef float f32x4 __attribute__((ext_vector_type(4)));

#define DH 256
#define G3 768
#define DIN 300
#define KL 320
#define NLEAF 16384

__device__ __forceinline__ float sigm(float x){ return 1.0f/(1.0f+expf(-x)); }

// Build split-f16 weight layouts: Bt[m][k] rows, m = colgroup-interleaved gates:
//   leaf/K2 (3 gates): m = 48*(j>>4) + g*16 + (j&15)
//   K1      (2 gates): m = 32*(j>>4) + gg*16 + (j&15), gg -> gate chunk gg+1
__global__ void prep_kernel(const float* __restrict__ Wx, const float* __restrict__ Wc,
                            const float* __restrict__ Ws, const float* __restrict__ bx,
                            const float* __restrict__ bs, const float* __restrict__ bc,
                            f16* __restrict__ BLh, f16* __restrict__ BLl,
                            f16* __restrict__ B1h, f16* __restrict__ B1l,
                            f16* __restrict__ B2h, f16* __restrict__ B2l,
                            float* __restrict__ bL, float* __restrict__ b1, float* __restrict__ b2){
    int idx = blockIdx.x*256 + threadIdx.x;
    const int nBL = G3*KL, nB1 = 512*DH, nB2 = G3*512;
    if (idx < nBL){
        int m = idx / KL, k = idx - m*KL;
        int blk = m/48, rem = m - blk*48, g = rem>>4, j = blk*16 + (rem&15);
        float v = (k < DIN) ? Wx[k*G3 + g*DH + j] : 0.0f;
        f16 h = (f16)v; BLh[idx] = h; BLl[idx] = (f16)(v - (float)h);
        return;
    }
    idx -= nBL;
    if (idx < nB1){
        int m = idx >> 8, k = idx & 255;
        int blk = m>>5, rem = m & 31, gg = rem>>4, j = blk*16 + (rem&15);
        float v = Wc[k*G3 + (gg+1)*DH + j];
        f16 h = (f16)v; B1h[idx] = h; B1l[idx] = (f16)(v - (float)h);
        return;
    }
    idx -= nB1;
    if (idx < nB2){
        int m = idx >> 9, k = idx & 511;
        int blk = m/48, rem = m - blk*48, g = rem>>4, j = blk*16 + (rem&15);
        float v = (k < DH) ? Wc[k*G3 + g*DH + j] : Ws[(k-DH)*G3 + g*DH + j];
        f16 h = (f16)v; B2h[idx] = h; B2l[idx] = (f16)(v - (float)h);
        return;
    }
    idx -= nB2;
    if (idx < G3){
        int blk = idx/48, rem = idx - blk*48, g = rem>>4, j = blk*16 + (rem&15);
        bL[idx] = bx[g*DH + j]; return;
    }
    idx -= G3;
    if (idx < 512){
        int blk = idx>>5, rem = idx & 31, gg = rem>>4, j = blk*16 + (rem&15);
        b1[idx] = bc[(gg+1)*DH+j] + bs[(gg+1)*DH+j]; return;
    }
    idx -= 512;
    if (idx < G3){
        int blk = idx/48, rem = idx - blk*48, g = rem>>4, j = blk*16 + (rem&15);
        b2[idx] = bc[g*DH+j] + bs[g*DH+j];
    }
}

// Generic split-f16 MFMA GEMM + gated epilogue.
// EP: 0=leaf(emb gather), 1=left-combine, 2=parent-combine (A = [h_odd | hl])
// Wave w owns col-group cg = blockIdx.y*4 + w: 16 cols x NG gate-tiles, RT row-tiles.
// A/B fragment mapping (gfx950 16x16x32): lane = row/col (&15), k-octet = lane>>4.
template<int EP, int RT, int NG, int KSTEPS>
__global__ __launch_bounds__(256) void gemm_kernel(
    const int* __restrict__ wid, const float* __restrict__ emb,
    const f16* __restrict__ A1h, const f16* __restrict__ A1l, const int sA1,
    const f16* __restrict__ A2h, const f16* __restrict__ A2l, const int sA2,
    const f16* __restrict__ Bh, const f16* __restrict__ Bl, const float* __restrict__ bias,
    const float* __restrict__ cChild, const float* __restrict__ cSib, const int sC,
    f16* __restrict__ oHh, f16* __restrict__ oHl, const int sH,
    float* __restrict__ oC, const int sCo, const int M)
{
    constexpr int K = KSTEPS*32;
    const int tid = threadIdx.x;
    const int lane = tid & 63;
    const int w = tid >> 6;
    const int cg = blockIdx.y*4 + w;
    const int l15 = lane & 15, lg = lane >> 4;
    const int rowbase = blockIdx.x * (RT*16);

    f32x4 acc[RT][NG];
    #pragma unroll
    for (int rt=0;rt<RT;++rt)
      #pragma unroll
      for (int g=0;g<NG;++g){ f32x4 z = {0.f,0.f,0.f,0.f}; acc[rt][g] = z; }

    const float* embp[RT];
    int ao1[RT], ao2[RT];
    #pragma unroll
    for (int rt=0;rt<RT;++rt){
        int r = rowbase + rt*16 + l15;
        int rc = (r < M) ? r : (M-1);
        if constexpr (EP==0){ embp[rt] = emb + wid[rc]*DIN + lg*8; }
        else { ao1[rt] = rc*sA1 + lg*8; ao2[rt] = rc*sA2 + lg*8; }
        (void)rc;
    }
    int bo[NG];
    #pragma unroll
    for (int g=0; g<NG; ++g) bo[g] = ((cg*NG+g)*16 + l15)*K + lg*8;

    #pragma unroll 2
    for (int kst=0; kst<KSTEPS; ++kst){
        f16x8 ah[RT], al[RT], bh[NG], bl[NG];
        if constexpr (EP==0){
            #pragma unroll
            for (int rt=0;rt<RT;++rt){
                float v[8];
                const float* ep = embp[rt] + kst*32;
                if (kst == KSTEPS-1){
                    int kb = kst*32 + lg*8;
                    #pragma unroll
                    for (int jj=0;jj<8;++jj) v[jj] = (kb + jj < DIN) ? ep[jj] : 0.0f;
                } else {
                    float4 u0 = *(const float4*)ep;
                    float4 u1 = *(const float4*)(ep+4);
                    v[0]=u0.x; v[1]=u0.y; v[2]=u0.z; v[3]=u0.w;
                    v[4]=u1.x; v[5]=u1.y; v[6]=u1.z; v[7]=u1.w;
                }
                #pragma unroll
                for (int jj=0;jj<8;++jj){ f16 hh=(f16)v[jj]; ah[rt][jj]=hh; al[rt][jj]=(f16)(v[jj]-(float)hh); }
            }
        } else {
            const bool u2 = (EP==2) && (kst >= KSTEPS/2);
            const int ko = (u2 ? (kst - KSTEPS/2) : kst) * 32;
            const f16* ph = u2 ? A2h : A1h;
            const f16* pl = u2 ? A2l : A1l;
            #pragma unroll
            for (int rt=0;rt<RT;++rt){
                int ao = u2 ? ao2[rt] : ao1[rt];
                ah[rt] = *(const f16x8*)(ph + ao + ko);
                al[rt] = *(const f16x8*)(pl + ao + ko);
            }
        }
        #pragma unroll
        for (int g=0;g<NG;++g){
            bh[g] = *(const f16x8*)(Bh + bo[g] + kst*32);
            bl[g] = *(const f16x8*)(Bl + bo[g] + kst*32);
        }
        #pragma unroll
        for (int rt=0;rt<RT;++rt)
          #pragma unroll
          for (int g=0;g<NG;++g){
            acc[rt][g] = __builtin_amdgcn_mfma_f32_16x16x32_f16(ah[rt], bh[g], acc[rt][g], 0,0,0);
            acc[rt][g] = __builtin_amdgcn_mfma_f32_16x16x32_f16(ah[rt], bl[g], acc[rt][g], 0,0,0);
            acc[rt][g] = __builtin_amdgcn_mfma_f32_16x16x32_f16(al[rt], bh[g], acc[rt][g], 0,0,0);
          }
    }

    float bv[NG];
    #pragma unroll
    for (int g=0;g<NG;++g) bv[g] = bias[(cg*NG+g)*16 + l15];
    const int j = cg*16 + l15;

    #pragma unroll
    for (int rt=0;rt<RT;++rt){
      #pragma unroll
      for (int reg=0;reg<4;++reg){
        int p = rowbase + rt*16 + lg*4 + reg;
        if (p < M){
            float cn, hn;
            if constexpr (EP==0){
                float gi = acc[rt][0][reg] + bv[0];
                float go = acc[rt][1][reg] + bv[1];
                float cp = acc[rt][2][reg] + bv[2];
                cn = sigm(gi)*tanhf(cp);
                hn = sigm(go)*tanhf(cn);
            } else if constexpr (EP==1){
                float gc = acc[rt][0][reg] + bv[0];
                float go = acc[rt][1][reg] + bv[1];
                cn = sigm(gc) * cChild[p*sC + j];
                hn = sigm(go)*tanhf(cn);
            } else {
                float gs = acc[rt][0][reg] + bv[0];
                float gc = acc[rt][1][reg] + bv[1];
                float go = acc[rt][2][reg] + bv[2];
                cn = sigm(gc)*cChild[p*sC + j] + sigm(gs)*cSib[p*sC + j];
                hn = sigm(go)*tanhf(cn);
            }
            oC[p*sCo + j] = cn;
            f16 hh = (f16)hn;
            oHh[p*sH + j] = hh;
            oHl[p*sH + j] = (f16)(hn - (float)hh);
        }
      }
    }
}

// Final combine (no sibling) on the root node, f32 dot with split-f16 weights (gates gc, go of B1).
__global__ void root_kernel(const f16* __restrict__ Hh, const f16* __restrict__ Hl,
        const float* __restrict__ C, const f16* __restrict__ B1h, const f16* __restrict__ B1l,
        const float* __restrict__ b1, float* __restrict__ out){
    __shared__ float hs[DH];
    const int j = threadIdx.x;
    hs[j] = (float)Hh[j] + (float)Hl[j];
    __syncthreads();
    int mgc = (j>>4)*32 + (j&15);
    int mgo = mgc + 16;
    float gc = 0.f, go = 0.f;
    for (int k=0;k<DH;++k){
        float wv_c = (float)B1h[mgc*DH + k] + (float)B1l[mgc*DH + k];
        float wv_o = (float)B1h[mgo*DH + k] + (float)B1l[mgo*DH + k];
        gc += hs[k]*wv_c; go += hs[k]*wv_o;
    }
    float cn = sigm(gc + b1[mgc]) * C[j];
    out[j] = sigm(go + b1[mgo]) * tanhf(cn);
}

extern "C" void kernel_launch(void* const* d_in, const int* in_sizes, int n_in,
                              void* d_out, int out_size, void* d_ws, size_t ws_size,
                              hipStream_t stream){
    const int* wid = (const int*)d_in[0];
    const float* emb = (const float*)d_in[1];
    const float* Wx = (const float*)d_in[2];
    const float* bx = (const float*)d_in[3];
    const float* Ws = (const float*)d_in[4];
    const float* bs = (const float*)d_in[5];
    const float* Wc = (const float*)d_in[6];
    const float* bc = (const float*)d_in[7];
    float* out = (float*)d_out;

    // Workspace layout. Tree stored in-place: node at level l lives at slot p*2^l
    // (h split-f16 hi/lo + c f32). hl needs its own buffer (its slots are read
    // full-width as A by other column-WGs of K2).
    char* p = (char*)d_ws;
    auto alloc = [&](size_t bytes){ void* r = (void*)p; p += (bytes + 255) & ~255ULL; return r; };
    f16* Hh = (f16*)alloc((size_t)NLEAF*DH*2);
    f16* Hl = (f16*)alloc((size_t)NLEAF*DH*2);
    float* C = (float*)alloc((size_t)NLEAF*DH*4);
    f16* HLh = (f16*)alloc((size_t)(NLEAF/2)*DH*2);
    f16* HLl = (f16*)alloc((size_t)(NLEAF/2)*DH*2);
    f16* BLh = (f16*)alloc((size_t)G3*KL*2); f16* BLl = (f16*)alloc((size_t)G3*KL*2);
    f16* B1h = (f16*)alloc((size_t)512*DH*2); f16* B1l = (f16*)alloc((size_t)512*DH*2);
    f16* B2h = (f16*)alloc((size_t)G3*512*2); f16* B2l = (f16*)alloc((size_t)G3*512*2);
    float* bL = (float*)alloc(G3*4);
    float* b1 = (float*)alloc(512*4);
    float* b2 = (float*)alloc(G3*4);

    const int nprep = G3*KL + 512*DH + G3*512 + G3 + 512 + G3;
    prep_kernel<<<(nprep+255)/256, 256, 0, stream>>>(Wx,Wc,Ws,bx,bs,bc,
        BLh,BLl,B1h,B1l,B2h,B2l,bL,b1,b2);

    // Leaf: [16384 x 320pad] @ BL -> h,c at slots 0..16383 (stride 1)
    gemm_kernel<0,4,3,10><<<dim3(NLEAF/64,4),256,0,stream>>>(
        wid, emb, nullptr,nullptr,0, nullptr,nullptr,0,
        BLh,BLl,bL, nullptr,nullptr,0, Hh,Hl,DH, C,DH, NLEAF);

    int s = 1;
    for (int P = NLEAF/2; P >= 1; P >>= 1){
        const int st = 2*s*DH;   // element stride between consecutive parents' child slots
        if (P >= 64){
            gemm_kernel<1,4,2,8><<<dim3(P/64,4),256,0,stream>>>(
                nullptr,nullptr, Hh,Hl,st, nullptr,nullptr,0,
                B1h,B1l,b1, C,nullptr,st, HLh,HLl,DH, C,st, P);
            gemm_kernel<2,4,3,16><<<dim3(P/64,4),256,0,stream>>>(
                nullptr,nullptr, Hh + s*DH, Hl + s*DH, st, HLh,HLl,DH,
                B2h,B2l,b2, C + s*DH, C, st, Hh,Hl,st, C,st, P);
        } else {
            const int gx = (P+15)/16;
            gemm_kernel<1,1,2,8><<<dim3(gx,4),256,0,stream>>>(
                nullptr,nullptr, Hh,Hl,st, nullptr,nullptr,0,
                B1h,B1l,b1, C,nullptr,st, HLh,HLl,DH, C,st, P);
            gemm_kernel<2,1,3,16><<<dim3(gx,4),256,0,stream>>>(
                nullptr,nullptr, Hh + s*DH, Hl + s*DH, st, HLh,HLl,DH,
                B2h,B2l,b2, C + s*DH, C, st, Hh,Hl,st, C,st, P);
        }
        s <<= 1;
    }
    root_kernel<<<1,DH,0,stream>>>(Hh,Hl,C,B1h,B1l,b1,out);
}